// Round 10
// baseline (99.807 us; speedup 1.0000x reference)
//
#include <hip/hip_runtime.h>

typedef __attribute__((ext_vector_type(8))) short bf16x8;
typedef __attribute__((ext_vector_type(4))) float f32x4;
typedef unsigned short u16;
typedef unsigned int u32;

#define NBLK 384

__device__ __forceinline__ u16 f2bf(float f) {
    u32 u = __builtin_bit_cast(u32, f);
    return (u16)((u + 0x7FFFu + ((u >> 16) & 1u)) >> 16);
}
__device__ __forceinline__ float sigm(float x) { return 1.f / (1.f + __expf(-x)); }
__device__ __forceinline__ float red16(float x) {
    x += __shfl_xor(x, 1, 64);
    x += __shfl_xor(x, 2, 64);
    x += __shfl_xor(x, 4, 64);
    x += __shfl_xor(x, 8, 64);
    return x;
}
__device__ __forceinline__ uint4 pack8(const float* s) {
    f32x4 v0 = *(const f32x4*)s;
    f32x4 v1 = *(const f32x4*)(s + 4);
    uint4 o;
    o.x = (u32)f2bf(v0.x) | ((u32)f2bf(v0.y) << 16);
    o.y = (u32)f2bf(v0.z) | ((u32)f2bf(v0.w) << 16);
    o.z = (u32)f2bf(v1.x) | ((u32)f2bf(v1.y) << 16);
    o.w = (u32)f2bf(v1.z) | ((u32)f2bf(v1.w) << 16);
    return o;
}

// ---------------- single kernel with software grid barrier -------------------
// Phase 1: W fp32 -> bf16 fragment order into ws.
//   wf layout: [mlp6][wave4][nt4][kk8][lane64][8] (65536 u16 per mlp)
// flag barrier (counter memset to 0 by host each call; all 384 blocks are
// co-resident by construction: 4-wave blocks @ ~120 VGPR -> 4 blocks/CU cap).
// Phase 2: R8 fused body; A-frags converted in-register from fp32 x.
struct PairTask {
    const float *xG, *xP;                   // fp32 inputs [2048][256]
    const u16 *WG, *WP;                     // B-frag tensors [4][4][8][64][8]
    const float *bG, *gmG, *beG;
    const float *bP, *gmP, *beP;
    const float *awG, *awP;                 // awG=apw (dots oG), awP=agw (dots oP)
    const float *attbP, *attbG;             // apb, agb
    float *outG, *outP;
    int interact;
};
struct MonoArgs { const float* W[6]; u16* wf; u32* cnt; PairTask p[3]; };

__global__ __launch_bounds__(256) void mono_kernel(MonoArgs a) {
    __shared__ float red_s[2][16][4];
    __shared__ float red_q[2][16][4];
    __shared__ float red_d[2][16][4];

    // ---------------- phase 1: W prep (R8 mapping, W only) -------------------
    int gid = blockIdx.x * 256 + threadIdx.x;    // 98304 threads, 49152 active
    if (gid < 49152) {
        int l = gid & 63, kk = (gid >> 6) & 7, nt = (gid >> 9) & 3,
            w = (gid >> 11) & 3, mlp = gid >> 13;
        int n = w * 64 + nt * 16 + (l & 15);
        int k0 = kk * 32 + (l >> 4) * 8;
        *(uint4*)(a.wf + (size_t)gid * 8) = pack8(a.W[mlp] + n * 256 + k0);
    }

    // ---------------- software grid barrier ----------------------------------
    __threadfence();                             // release wf (device scope)
    __syncthreads();                             // all block writes issued
    if (threadIdx.x == 0) {
        __atomic_fetch_add(a.cnt, 1u, __ATOMIC_RELEASE);
        while (__atomic_load_n(a.cnt, __ATOMIC_RELAXED) < (u32)NBLK)
            __builtin_amdgcn_s_sleep(2);
    }
    __syncthreads();
    __threadfence();                             // acquire before reading wf

    // ---------------- phase 2: fused GEMM + LN + ReLU + interaction ----------
    int wg = blockIdx.x;
    int swz = (wg & 7) * 48 + (wg >> 3);    // XCD swizzle, 384 % 8 == 0, bijective
    int pair = swz >> 7;
    int mt = swz & 127;
    PairTask tk = a.p[pair];

    int tid = threadIdx.x;
    int wave = tid >> 6;
    int lane = tid & 63;
    int cq = lane & 15, rq = lane >> 4;

    // hoisted epilogue parameters (latency hides under MFMA loop)
    float bb[2][4], gm[2][4], be[2][4], aw[2][4];
#pragma unroll
    for (int g = 0; g < 2; ++g)
#pragma unroll
        for (int nt = 0; nt < 4; ++nt) {
            int c = wave * 64 + nt * 16 + cq;
            bb[g][nt] = g ? tk.bP[c] : tk.bG[c];
            gm[g][nt] = g ? tk.gmP[c] : tk.gmG[c];
            be[g][nt] = g ? tk.beP[c] : tk.beG[c];
            aw[g][nt] = tk.interact ? (g ? tk.awP[c] : tk.awG[c]) : 0.f;
        }
    float battP = tk.interact ? *tk.attbP : 0.f;
    float battG = tk.interact ? *tk.attbG : 0.f;

    // A fragments: own 16 rows of both gemms, fp32 load + in-register convert
    const float* xg = tk.xG + (size_t)(mt * 16 + cq) * 256 + rq * 8;
    const float* xp = tk.xP + (size_t)(mt * 16 + cq) * 256 + rq * 8;
    bf16x8 aF[2][8];
#pragma unroll
    for (int kk = 0; kk < 8; ++kk) {
        aF[0][kk] = __builtin_bit_cast(bf16x8, pack8(xg + kk * 32));
        aF[1][kk] = __builtin_bit_cast(bf16x8, pack8(xp + kk * 32));
    }

    f32x4 acc[2][4];
#pragma unroll
    for (int g = 0; g < 2; ++g)
#pragma unroll
        for (int nt = 0; nt < 4; ++nt) acc[g][nt] = (f32x4){0.f, 0.f, 0.f, 0.f};

    const u16* wb0 = tk.WG + (size_t)wave * 16384 + lane * 8;
    const u16* wb1 = tk.WP + (size_t)wave * 16384 + lane * 8;

    // main loop: 64 independent B loads + 64 MFMAs, no barriers
#pragma unroll
    for (int kk = 0; kk < 8; ++kk) {
#pragma unroll
        for (int nt = 0; nt < 4; ++nt) {
            bf16x8 b0 = *(const bf16x8*)(wb0 + (size_t)(nt * 8 + kk) * 512);
            acc[0][nt] = __builtin_amdgcn_mfma_f32_16x16x32_bf16(aF[0][kk], b0, acc[0][nt], 0, 0, 0);
            bf16x8 b1 = *(const bf16x8*)(wb1 + (size_t)(nt * 8 + kk) * 512);
            acc[1][nt] = __builtin_amdgcn_mfma_f32_16x16x32_bf16(aF[1][kk], b1, acc[1][nt], 0, 0, 0);
        }
    }

    // epilogue
    float v[2][4][4];
#pragma unroll
    for (int r = 0; r < 4; ++r) {
#pragma unroll
        for (int g = 0; g < 2; ++g) {
            float s = 0.f, q = 0.f;
#pragma unroll
            for (int nt = 0; nt < 4; ++nt) {
                float t = acc[g][nt][r] + bb[g][nt];
                v[g][nt][r] = t;
                s += t; q += t * t;
            }
            s = red16(s); q = red16(q);
            if (cq == 0) {
                red_s[g][rq * 4 + r][wave] = s;
                red_q[g][rq * 4 + r][wave] = q;
            }
        }
    }
    __syncthreads();

    float o[2][4][4];
#pragma unroll
    for (int r = 0; r < 4; ++r) {
        int row = rq * 4 + r;
#pragma unroll
        for (int g = 0; g < 2; ++g) {
            f32x4 s4 = *(const f32x4*)&red_s[g][row][0];
            f32x4 q4 = *(const f32x4*)&red_q[g][row][0];
            float s = s4.x + s4.y + s4.z + s4.w;
            float q = q4.x + q4.y + q4.z + q4.w;
            float mean = s * (1.f / 256.f);
            float var = q * (1.f / 256.f) - mean * mean;
            float rstd = rsqrtf(var + 1e-5f);
#pragma unroll
            for (int nt = 0; nt < 4; ++nt)
                o[g][nt][r] = fmaxf((v[g][nt][r] - mean) * rstd * gm[g][nt] + be[g][nt], 0.f);
        }
    }

    if (!tk.interact) {
#pragma unroll
        for (int r = 0; r < 4; ++r) {
            int grow = mt * 16 + rq * 4 + r;
#pragma unroll
            for (int nt = 0; nt < 4; ++nt) {
                int c = wave * 64 + nt * 16 + cq;
                tk.outG[(size_t)grow * 256 + c] = o[0][nt][r];
                tk.outP[(size_t)grow * 256 + c] = o[1][nt][r];
            }
        }
    } else {
#pragma unroll
        for (int r = 0; r < 4; ++r) {
            float dg = 0.f, dp = 0.f;
#pragma unroll
            for (int nt = 0; nt < 4; ++nt) {
                dg += o[0][nt][r] * aw[0][nt];
                dp += o[1][nt][r] * aw[1][nt];
            }
            dg = red16(dg); dp = red16(dp);
            if (cq == 0) {
                red_d[0][rq * 4 + r][wave] = dg;
                red_d[1][rq * 4 + r][wave] = dp;
            }
        }
        __syncthreads();
#pragma unroll
        for (int r = 0; r < 4; ++r) {
            int row = rq * 4 + r;
            f32x4 d4 = *(const f32x4*)&red_d[0][row][0];
            f32x4 e4 = *(const f32x4*)&red_d[1][row][0];
            float dG = d4.x + d4.y + d4.z + d4.w;   // dot(g_align, apw)
            float dP = e4.x + e4.y + e4.z + e4.w;   // dot(p_align, agw)
            int grow = mt * 16 + row;
#pragma unroll
            for (int nt = 0; nt < 4; ++nt) {
                int c = wave * 64 + nt * 16 + cq;
                float og = o[0][nt][r], op = o[1][nt][r];
                tk.outG[(size_t)grow * 256 + c] =
                    op * sigm(op * dG + battP) + og * sigm(og * dP + battG);
            }
        }
    }
}

// -----------------------------------------------------------------------------
extern "C" void kernel_launch(void* const* d_in, const int* in_sizes, int n_in,
                              void* d_out, int out_size, void* d_ws, size_t ws_size,
                              hipStream_t stream) {
    const float* gfeat = (const float*)d_in[0];
    const float* pfeat = (const float*)d_in[1];
    float* out = (float*)d_out;
    const size_t S = (size_t)2048 * 256;

    float* out_common = out + 0 * S;
    float* out_syn    = out + 1 * S;
    float* out_gspec  = out + 2 * S;
    float* out_pspec  = out + 3 * S;

    u16* wf = (u16*)d_ws;                   // 6 * 65536 u16
    u32* cnt = (u32*)(wf + 6 * 65536);      // barrier counter

    // reset barrier counter each call (graph-capturable, stream-ordered)
    hipMemsetAsync(cnt, 0, sizeof(u32), stream);

    MonoArgs ma;
    ma.W[0] = (const float*)d_in[2];    // gs_W
    ma.W[1] = (const float*)d_in[6];    // ps_W
    ma.W[2] = (const float*)d_in[10];   // c_g_W
    ma.W[3] = (const float*)d_in[14];   // c_p_W
    ma.W[4] = (const float*)d_in[22];   // s_g_W
    ma.W[5] = (const float*)d_in[26];   // s_p_W
    ma.wf = wf;
    ma.cnt = cnt;

    // pair 0: spec — G: mlp(gfeat, gs_*) -> g_spec ; P: mlp(pfeat, ps_*) -> p_spec
    ma.p[0] = { gfeat, pfeat, wf + 0 * 65536, wf + 1 * 65536,
                (const float*)d_in[3], (const float*)d_in[4], (const float*)d_in[5],
                (const float*)d_in[7], (const float*)d_in[8], (const float*)d_in[9],
                nullptr, nullptr, nullptr, nullptr,
                out_gspec, out_pspec, 0 };
    // pair 1: common — G: mlp(pfeat, c_g_*), P: mlp(gfeat, c_p_*)
    ma.p[1] = { pfeat, gfeat, wf + 2 * 65536, wf + 3 * 65536,
                (const float*)d_in[11], (const float*)d_in[12], (const float*)d_in[13],
                (const float*)d_in[15], (const float*)d_in[16], (const float*)d_in[17],
                (const float*)d_in[20] /*c_apw*/, (const float*)d_in[18] /*c_agw*/,
                (const float*)d_in[21] /*c_apb*/, (const float*)d_in[19] /*c_agb*/,
                out_common, nullptr, 1 };
    // pair 2: synergy — G: mlp(pfeat, s_g_*), P: mlp(gfeat, s_p_*)
    ma.p[2] = { pfeat, gfeat, wf + 4 * 65536, wf + 5 * 65536,
                (const float*)d_in[23], (const float*)d_in[24], (const float*)d_in[25],
                (const float*)d_in[27], (const float*)d_in[28], (const float*)d_in[29],
                (const float*)d_in[32] /*s_apw*/, (const float*)d_in[30] /*s_agw*/,
                (const float*)d_in[33] /*s_apb*/, (const float*)d_in[31] /*s_agb*/,
                out_syn, nullptr, 1 };

    hipLaunchKernelGGL(mono_kernel, dim3(NBLK), dim3(256), 0, stream, ma);
}

// Round 11
// 25.746 us; speedup vs baseline: 3.8767x; 3.8767x over previous
//
#include <hip/hip_runtime.h>

typedef __attribute__((ext_vector_type(8))) short bf16x8;
typedef __attribute__((ext_vector_type(4))) float f32x4;
typedef unsigned short u16;
typedef unsigned int u32;

__device__ __forceinline__ u16 f2bf(float f) {
    u32 u = __builtin_bit_cast(u32, f);
    return (u16)((u + 0x7FFFu + ((u >> 16) & 1u)) >> 16);
}
__device__ __forceinline__ float sigm(float x) { return 1.f / (1.f + __expf(-x)); }
__device__ __forceinline__ float red16(float x) {
    x += __shfl_xor(x, 1, 64);
    x += __shfl_xor(x, 2, 64);
    x += __shfl_xor(x, 4, 64);
    x += __shfl_xor(x, 8, 64);
    return x;
}
__device__ __forceinline__ uint4 pack8(const float* s) {
    f32x4 v0 = *(const f32x4*)s;
    f32x4 v1 = *(const f32x4*)(s + 4);
    uint4 o;
    o.x = (u32)f2bf(v0.x) | ((u32)f2bf(v0.y) << 16);
    o.y = (u32)f2bf(v0.z) | ((u32)f2bf(v0.w) << 16);
    o.z = (u32)f2bf(v1.x) | ((u32)f2bf(v1.y) << 16);
    o.w = (u32)f2bf(v1.z) | ((u32)f2bf(v1.w) << 16);
    return o;
}

// ---------------- prep: fragment-order convert + per-XCD W replication -------
// wf layout: [rep][mlp6][wave4][nt4][kk8][lane64][8]  (49152 uint4 per replica)
// xf layout: [tensor2][mt128][kk8][lane64][8]          (524288 u16 per tensor)
struct PrepArgs {
    const float* W[6]; const float* xg; const float* xp;
    u16* wf; u16* xf; int nrep;
};

__global__ __launch_bounds__(256) void prep_kernel(PrepArgs a) {
    int blk = blockIdx.x, tid = threadIdx.x;
    int wblk = 192 * a.nrep;
    if (blk < wblk) {
        int rep = (a.nrep == 8) ? (blk & 7) : 0;
        int gid = ((a.nrep == 8) ? (blk >> 3) : blk) * 256 + tid;   // 0..49151
        int l = gid & 63, kk = (gid >> 6) & 7, nt = (gid >> 9) & 3,
            w = (gid >> 11) & 3, mlp = gid >> 13;
        int n = w * 64 + nt * 16 + (l & 15);
        int k0 = kk * 32 + (l >> 4) * 8;
        *(uint4*)(a.wf + ((size_t)rep * 49152 + gid) * 8) =
            pack8(a.W[mlp] + n * 256 + k0);
    } else {
        int r = (blk - wblk) * 256 + tid;                           // 0..131071
        const float* x = (r >> 16) ? a.xp : a.xg;
        int q = r & 65535;
        int l = q & 63, kk = (q >> 6) & 7, mt = q >> 9;
        int row = mt * 16 + (l & 15);
        int k0 = kk * 32 + (l >> 4) * 8;
        *(uint4*)(a.xf + (size_t)r * 8) = pack8(x + row * 256 + k0);
    }
}

// ---------------- fused (R8 + XCD-local replicas + depth-2 prefetch) ---------
// 384 blocks = (pair:3, mt:128). 256 thr = 4 waves; wave owns N cols
// [wave*64, wave*64+64) for BOTH gemms. No LDS/barriers in main loop.
struct PairTask {
    const u16 *xfG, *xfP;                   // A-frag tensors [128][8][64][8]
    int mlpG, mlpP;                         // B-frag tensor indices in wf
    const float *bG, *gmG, *beG;
    const float *bP, *gmP, *beP;
    const float *awG, *awP;                 // awG=apw (dots oG), awP=agw (dots oP)
    const float *attbP, *attbG;             // apb, agb
    float *outG, *outP;
    int interact;
};
struct FusedArgs { const u16* wf; int nrep; PairTask p[3]; };

__global__ __launch_bounds__(256, 2) void fused_kernel(FusedArgs args) {
    __shared__ float red_s[2][16][4];
    __shared__ float red_q[2][16][4];
    __shared__ float red_d[2][16][4];

    int wg = blockIdx.x;
    int swz = (wg & 7) * 48 + (wg >> 3);    // XCD swizzle, 384 % 8 == 0, bijective
    int pair = swz >> 7;
    int mt = swz & 127;
    PairTask tk = args.p[pair];
    int rep = (wg & 7) % args.nrep;         // XCD-local replica (heuristic, safe)

    int tid = threadIdx.x;
    int wave = tid >> 6;
    int lane = tid & 63;
    int cq = lane & 15, rq = lane >> 4;

    // hoisted epilogue parameters (latency hides under MFMA loop)
    float bb[2][4], gm[2][4], be[2][4], aw[2][4];
#pragma unroll
    for (int g = 0; g < 2; ++g)
#pragma unroll
        for (int nt = 0; nt < 4; ++nt) {
            int c = wave * 64 + nt * 16 + cq;
            bb[g][nt] = g ? tk.bP[c] : tk.bG[c];
            gm[g][nt] = g ? tk.gmP[c] : tk.gmG[c];
            be[g][nt] = g ? tk.beP[c] : tk.beG[c];
            aw[g][nt] = tk.interact ? (g ? tk.awP[c] : tk.awG[c]) : 0.f;
        }
    float battP = tk.interact ? *tk.attbP : 0.f;
    float battG = tk.interact ? *tk.attbG : 0.f;

    f32x4 acc[2][4];
#pragma unroll
    for (int g = 0; g < 2; ++g)
#pragma unroll
        for (int nt = 0; nt < 4; ++nt) acc[g][nt] = (f32x4){0.f, 0.f, 0.f, 0.f};

    const u16* xaG = tk.xfG + ((size_t)mt * 8 * 64 + lane) * 8;
    const u16* xaP = tk.xfP + ((size_t)mt * 8 * 64 + lane) * 8;
    const u16* wb0 = args.wf + ((size_t)rep * 6 + tk.mlpG) * 65536
                             + (size_t)wave * 16384 + lane * 8;
    const u16* wb1 = args.wf + ((size_t)rep * 6 + tk.mlpP) * 65536
                             + (size_t)wave * 16384 + lane * 8;

    // ---- depth-2 software pipeline: stage s holds kk's 2 A-frags + 8 B-frags
    bf16x8 bufA0[3], bufA1[3], bufB[3][8];
#define ISSUE(KK, S)                                                       \
    do {                                                                   \
        bufA0[S] = *(const bf16x8*)(xaG + (KK) * 512);                     \
        bufA1[S] = *(const bf16x8*)(xaP + (KK) * 512);                     \
        _Pragma("unroll")                                                  \
        for (int nt = 0; nt < 4; ++nt) {                                   \
            bufB[S][nt]     = *(const bf16x8*)(wb0 + ((size_t)(nt * 8 + (KK)) * 512)); \
            bufB[S][4 + nt] = *(const bf16x8*)(wb1 + ((size_t)(nt * 8 + (KK)) * 512)); \
        }                                                                  \
    } while (0)

    ISSUE(0, 0);
    ISSUE(1, 1);
#pragma unroll
    for (int kk = 0; kk < 8; ++kk) {
        const int s = kk % 3;
        if (kk + 2 < 8) ISSUE(kk + 2, (kk + 2) % 3);
#pragma unroll
        for (int nt = 0; nt < 4; ++nt) {
            acc[0][nt] = __builtin_amdgcn_mfma_f32_16x16x32_bf16(bufA0[s], bufB[s][nt], acc[0][nt], 0, 0, 0);
            acc[1][nt] = __builtin_amdgcn_mfma_f32_16x16x32_bf16(bufA1[s], bufB[s][4 + nt], acc[1][nt], 0, 0, 0);
        }
    }
#undef ISSUE

    // ---------------------------- epilogue ----------------------------------
    float v[2][4][4];
#pragma unroll
    for (int r = 0; r < 4; ++r) {
#pragma unroll
        for (int g = 0; g < 2; ++g) {
            float s = 0.f, q = 0.f;
#pragma unroll
            for (int nt = 0; nt < 4; ++nt) {
                float t = acc[g][nt][r] + bb[g][nt];
                v[g][nt][r] = t;
                s += t; q += t * t;
            }
            s = red16(s); q = red16(q);
            if (cq == 0) {
                red_s[g][rq * 4 + r][wave] = s;
                red_q[g][rq * 4 + r][wave] = q;
            }
        }
    }
    __syncthreads();

    float o[2][4][4];
#pragma unroll
    for (int r = 0; r < 4; ++r) {
        int row = rq * 4 + r;
#pragma unroll
        for (int g = 0; g < 2; ++g) {
            f32x4 s4 = *(const f32x4*)&red_s[g][row][0];
            f32x4 q4 = *(const f32x4*)&red_q[g][row][0];
            float s = s4.x + s4.y + s4.z + s4.w;
            float q = q4.x + q4.y + q4.z + q4.w;
            float mean = s * (1.f / 256.f);
            float var = q * (1.f / 256.f) - mean * mean;
            float rstd = rsqrtf(var + 1e-5f);
#pragma unroll
            for (int nt = 0; nt < 4; ++nt)
                o[g][nt][r] = fmaxf((v[g][nt][r] - mean) * rstd * gm[g][nt] + be[g][nt], 0.f);
        }
    }

    if (!tk.interact) {
#pragma unroll
        for (int r = 0; r < 4; ++r) {
            int grow = mt * 16 + rq * 4 + r;
#pragma unroll
            for (int nt = 0; nt < 4; ++nt) {
                int c = wave * 64 + nt * 16 + cq;
                tk.outG[(size_t)grow * 256 + c] = o[0][nt][r];
                tk.outP[(size_t)grow * 256 + c] = o[1][nt][r];
            }
        }
    } else {
#pragma unroll
        for (int r = 0; r < 4; ++r) {
            float dg = 0.f, dp = 0.f;
#pragma unroll
            for (int nt = 0; nt < 4; ++nt) {
                dg += o[0][nt][r] * aw[0][nt];
                dp += o[1][nt][r] * aw[1][nt];
            }
            dg = red16(dg); dp = red16(dp);
            if (cq == 0) {
                red_d[0][rq * 4 + r][wave] = dg;
                red_d[1][rq * 4 + r][wave] = dp;
            }
        }
        __syncthreads();
#pragma unroll
        for (int r = 0; r < 4; ++r) {
            int row = rq * 4 + r;
            f32x4 d4 = *(const f32x4*)&red_d[0][row][0];
            f32x4 e4 = *(const f32x4*)&red_d[1][row][0];
            float dG = d4.x + d4.y + d4.z + d4.w;   // dot(g_align, apw)
            float dP = e4.x + e4.y + e4.z + e4.w;   // dot(p_align, agw)
            int grow = mt * 16 + row;
#pragma unroll
            for (int nt = 0; nt < 4; ++nt) {
                int c = wave * 64 + nt * 16 + cq;
                float og = o[0][nt][r], op = o[1][nt][r];
                tk.outG[(size_t)grow * 256 + c] =
                    op * sigm(op * dG + battP) + og * sigm(og * dP + battG);
            }
        }
    }
}

// -----------------------------------------------------------------------------
extern "C" void kernel_launch(void* const* d_in, const int* in_sizes, int n_in,
                              void* d_out, int out_size, void* d_ws, size_t ws_size,
                              hipStream_t stream) {
    const float* gfeat = (const float*)d_in[0];
    const float* pfeat = (const float*)d_in[1];
    float* out = (float*)d_out;
    const size_t S = (size_t)2048 * 256;

    float* out_common = out + 0 * S;
    float* out_syn    = out + 1 * S;
    float* out_gspec  = out + 2 * S;
    float* out_pspec  = out + 3 * S;

    // ws: [nrep * 786432 u16 wf][1048576 u16 xf]
    const size_t WF_REP = (size_t)49152 * 8;            // u16 per replica
    int nrep = (ws_size >= (8 * WF_REP + 2 * 524288) * sizeof(u16) + 4096) ? 8 : 1;
    u16* wf = (u16*)d_ws;
    u16* xf = wf + (size_t)nrep * WF_REP;
    u16* xf_g = xf;
    u16* xf_p = xf + 524288;

    PrepArgs pa;
    pa.W[0] = (const float*)d_in[2];    // gs_W
    pa.W[1] = (const float*)d_in[6];    // ps_W
    pa.W[2] = (const float*)d_in[10];   // c_g_W
    pa.W[3] = (const float*)d_in[14];   // c_p_W
    pa.W[4] = (const float*)d_in[22];   // s_g_W
    pa.W[5] = (const float*)d_in[26];   // s_p_W
    pa.xg = gfeat; pa.xp = pfeat;
    pa.wf = wf; pa.xf = xf; pa.nrep = nrep;
    hipLaunchKernelGGL(prep_kernel, dim3(192 * nrep + 512), dim3(256), 0, stream, pa);

    FusedArgs fa;
    fa.wf = wf; fa.nrep = nrep;
    // pair 0: spec — G: mlp(gfeat, gs_*) -> g_spec ; P: mlp(pfeat, ps_*) -> p_spec
    fa.p[0] = { xf_g, xf_p, 0, 1,
                (const float*)d_in[3], (const float*)d_in[4], (const float*)d_in[5],
                (const float*)d_in[7], (const float*)d_in[8], (const float*)d_in[9],
                nullptr, nullptr, nullptr, nullptr,
                out_gspec, out_pspec, 0 };
    // pair 1: common — G: mlp(pfeat, c_g_*), P: mlp(gfeat, c_p_*)
    fa.p[1] = { xf_p, xf_g, 2, 3,
                (const float*)d_in[11], (const float*)d_in[12], (const float*)d_in[13],
                (const float*)d_in[15], (const float*)d_in[16], (const float*)d_in[17],
                (const float*)d_in[20] /*c_apw*/, (const float*)d_in[18] /*c_agw*/,
                (const float*)d_in[21] /*c_apb*/, (const float*)d_in[19] /*c_agb*/,
                out_common, nullptr, 1 };
    // pair 2: synergy — G: mlp(pfeat, s_g_*), P: mlp(gfeat, s_p_*)
    fa.p[2] = { xf_p, xf_g, 4, 5,
                (const float*)d_in[23], (const float*)d_in[24], (const float*)d_in[25],
                (const float*)d_in[27], (const float*)d_in[28], (const float*)d_in[29],
                (const float*)d_in[32] /*s_apw*/, (const float*)d_in[30] /*s_agw*/,
                (const float*)d_in[33] /*s_apb*/, (const float*)d_in[31] /*s_agb*/,
                out_syn, nullptr, 1 };

    hipLaunchKernelGGL(fused_kernel, dim3(384), dim3(256), 0, stream, fa);
}